// Round 4
// baseline (600.381 us; speedup 1.0000x reference)
//
#include <hip/hip_runtime.h>
#include <cstdint>

#define HID 1024
#define FFN 4096
#define NE 8
#define NT 4096
#define NTP 4224  // NT + 128 slack rows so tail m-tiles read in-bounds garbage

typedef __bf16 bf16x8 __attribute__((ext_vector_type(8)));
typedef unsigned short ushortx8 __attribute__((ext_vector_type(8)));
typedef float f32x4 __attribute__((ext_vector_type(4)));

// ---- ws layout (bytes) ----
// 0      counts[8] | 32 cursor[8] | 64 prob_sum[8] | 96 offsets[8]
// 256    perm[NT]        (16384)
// 16640  wgt[NT]         (16384)
// 33024  eidx[NT]        (16384)
// 49408  wgtg[NT]        (16384)   gate weight in expert-sorted order
// 65792  xg[NTP*HID]     bf16 gathered tokens   (8.65 MB)
// 8716544   w1b          bf16 fc1_w             (67.1 MB)
// 75825408  hbuf[NTP*FFN] bf16 activations      (34.6 MB)
// 110428416 w2b          bf16 fc2_w             (67.1 MB)
// total ~177.5 MB

__device__ __forceinline__ unsigned cvt2(float a, float b) {
  unsigned ua = __float_as_uint(a), ub = __float_as_uint(b);
  ua = (ua + 0x7fffu + ((ua >> 16) & 1u)) >> 16;
  ub = (ub + 0x7fffu + ((ub >> 16) & 1u)) >> 16;
  return ua | (ub << 16);
}
__device__ __forceinline__ unsigned short f2bf(float a) {
  unsigned ua = __float_as_uint(a);
  return (unsigned short)((ua + 0x7fffu + ((ua >> 16) & 1u)) >> 16);
}
// async global->LDS, 16B per lane; LDS dest = wave-uniform base + lane*16
__device__ __forceinline__ void ldg16(const unsigned short* g, unsigned short* l) {
  __builtin_amdgcn_global_load_lds((const __attribute__((address_space(1))) void*)g,
                                   (__attribute__((address_space(3))) void*)l, 16, 0, 0);
}

// ---------------- fp32 -> bf16 weight convert (w1 and w2) ----------------
__global__ __launch_bounds__(256) void wcvt_kernel(const float* __restrict__ w1,
                                                   const float* __restrict__ w2,
                                                   unsigned short* __restrict__ w1b,
                                                   unsigned short* __restrict__ w2b) {
  size_t t = (size_t)blockIdx.x * 256 + threadIdx.x;
  const size_t half = (size_t)NE * FFN * HID / 8;  // threads per tensor
  const float* src;
  unsigned short* dst;
  size_t i;
  if (t < half) { src = w1; dst = w1b; i = t; }
  else          { src = w2; dst = w2b; i = t - half; }
  float4 v0 = *(const float4*)(src + i * 8);
  float4 v1 = *(const float4*)(src + i * 8 + 4);
  uint4 o;
  o.x = cvt2(v0.x, v0.y); o.y = cvt2(v0.z, v0.w);
  o.z = cvt2(v1.x, v1.y); o.w = cvt2(v1.z, v1.w);
  *(uint4*)(dst + i * 8) = o;
}

// ---------------- router: fp32 exact, one wave per token ----------------
__global__ __launch_bounds__(256) void router_kernel(
    const float* __restrict__ x, const float* __restrict__ rw,
    int* __restrict__ counts, float* __restrict__ prob_sum,
    int* __restrict__ eidx, float* __restrict__ wgt) {
  __shared__ float rsm[NE * HID];
  __shared__ float pshare[4][NE];
  for (int i = threadIdx.x; i < NE * HID; i += 256) rsm[i] = rw[i];
  __syncthreads();
  int wave = threadIdx.x >> 6, lane = threadIdx.x & 63;
  int t = blockIdx.x * 4 + wave;
  const float* xr = x + (size_t)t * HID;
  float acc[NE];
#pragma unroll
  for (int e = 0; e < NE; e++) acc[e] = 0.f;
#pragma unroll
  for (int j = 0; j < HID / 64; j++) {
    float xv = xr[j * 64 + lane];
#pragma unroll
    for (int e = 0; e < NE; e++) acc[e] = fmaf(xv, rsm[e * HID + j * 64 + lane], acc[e]);
  }
#pragma unroll
  for (int off = 32; off > 0; off >>= 1) {
#pragma unroll
    for (int e = 0; e < NE; e++) acc[e] += __shfl_down(acc[e], off);
  }
  if (lane == 0) {
    float mx = acc[0]; int mi = 0;
#pragma unroll
    for (int e = 1; e < NE; e++) if (acc[e] > mx) { mx = acc[e]; mi = e; }
    float pr[NE], se = 0.f;
#pragma unroll
    for (int e = 0; e < NE; e++) { pr[e] = expf(acc[e] - mx); se += pr[e]; }
    float inv = 1.f / se;
    wgt[t] = pr[mi] * inv;
    eidx[t] = mi;
    atomicAdd(&counts[mi], 1);
#pragma unroll
    for (int e = 0; e < NE; e++) pshare[wave][e] = pr[e] * inv;
  }
  __syncthreads();
  if (threadIdx.x < NE) {
    float s = pshare[0][threadIdx.x] + pshare[1][threadIdx.x] +
              pshare[2][threadIdx.x] + pshare[3][threadIdx.x];
    atomicAdd(&prob_sum[threadIdx.x], s);
  }
}

// ---------------- offsets scan + aux loss ----------------
__global__ void scan_aux_kernel(const int* __restrict__ counts,
                                const float* __restrict__ prob_sum,
                                int* __restrict__ offsets,
                                float* __restrict__ aux_out) {
  if (threadIdx.x == 0) {
    int off = 0; float s = 0.f;
    for (int e = 0; e < NE; e++) {
      offsets[e] = off;
      off += counts[e];
      s += (prob_sum[e] / (float)NT) * ((float)counts[e] / (float)NT);
    }
    *aux_out = 0.01f * (float)NE * s;
  }
}

// ---------------- group tokens by expert ----------------
__global__ void bucketize_kernel(const int* __restrict__ eidx,
                                 const int* __restrict__ offsets,
                                 int* __restrict__ cursor, int* __restrict__ perm) {
  int t = blockIdx.x * 256 + threadIdx.x;
  int e = eidx[t];
  int slot = atomicAdd(&cursor[e], 1);
  perm[offsets[e] + slot] = t;
}

// ---------------- gather tokens into expert-sorted bf16 rows ----------------
__global__ __launch_bounds__(256) void xgather_kernel(
    const float* __restrict__ x, const int* __restrict__ perm,
    const float* __restrict__ wgt, unsigned short* __restrict__ xg,
    float* __restrict__ wgtg) {
  int row = blockIdx.x;
  int tok = perm[row];
  float4 v = ((const float4*)(x + (size_t)tok * HID))[threadIdx.x];
  uint2 o; o.x = cvt2(v.x, v.y); o.y = cvt2(v.z, v.w);
  ((uint2*)(xg + (size_t)row * HID))[threadIdx.x] = o;
  if (threadIdx.x == 0) wgtg[row] = wgt[tok];
}

// ===== shared GEMM tiling =====
// M128 x N128 tile, BK=32 bf16 (64B/row). LDS tiles 128x32 unpadded with
// 16B-block XOR swizzle: block kb for row r stored at slot kb ^ ((r+(r>>2))&3).
// Gives 2-way (free) ds_read_b128 bank aliasing; compatible with
// global_load_lds lane-contiguous placement. Double-buffered, 1 barrier/iter.

// ---------------- GEMM1: H = gelu(Xg W1^T + b1) ----------------
__global__ __launch_bounds__(256, 4) void gemm1_kernel(
    const unsigned short* __restrict__ xg, const unsigned short* __restrict__ w1b,
    const float* __restrict__ b1, const int* __restrict__ counts,
    const int* __restrict__ offsets, unsigned short* __restrict__ hbuf) {
  int e = blockIdx.z;
  int Nexp = counts[e];
  int m0 = blockIdx.y * 128;
  if (m0 >= Nexp) return;
  int n0 = blockIdx.x * 128;
  int gbase = offsets[e] + m0;

  __shared__ unsigned short As[2][128 * 32];
  __shared__ unsigned short Bs[2][128 * 32];

  int tid = threadIdx.x, lane = tid & 63, w = tid >> 6;
  // DMA source mapping: lane -> (row = rl, 16B-block kbp), swizzled global col
  int rl = lane >> 2, kbp = lane & 3;
  int rA0 = w * 32 + rl, rA1 = rA0 + 16;
  int s0 = (rA0 + (rA0 >> 2)) & 3, s1 = (rA1 + (rA1 >> 2)) & 3;
  const unsigned short* w1e = w1b + (size_t)e * (FFN * HID);
  const unsigned short* ga0 = xg + (size_t)(gbase + rA0) * HID + (kbp ^ s0) * 8;
  const unsigned short* ga1 = xg + (size_t)(gbase + rA1) * HID + (kbp ^ s1) * 8;
  const unsigned short* gb0 = w1e + (size_t)(n0 + rA0) * HID + (kbp ^ s0) * 8;
  const unsigned short* gb1 = w1e + (size_t)(n0 + rA1) * HID + (kbp ^ s1) * 8;
  const int ld0 = (w * 32) * 32, ld1 = (w * 32 + 16) * 32;  // ushort idx

  int wm = w & 1, wn = w >> 1, quad = lane >> 4, l15 = lane & 15;
  int sl = (l15 + (l15 >> 2)) & 3;
  const int aoff = (wm * 64 + l15) * 32 + (quad ^ sl) * 8;
  const int boff = (wn * 64 + l15) * 32 + (quad ^ sl) * 8;
  f32x4 acc[4][4] = {};

  // prologue -> buf0
  ldg16(ga0, &As[0][ld0]); ldg16(ga1, &As[0][ld1]);
  ldg16(gb0, &Bs[0][ld0]); ldg16(gb1, &Bs[0][ld1]);
  ga0 += 32; ga1 += 32; gb0 += 32; gb1 += 32;
  __syncthreads();

  const int NK = HID / 32;  // 32
  for (int kk = 0; kk < NK; kk++) {
    int cur = kk & 1;
    if (kk + 1 < NK) {
      int nb = cur ^ 1;
      ldg16(ga0, &As[nb][ld0]); ldg16(ga1, &As[nb][ld1]);
      ldg16(gb0, &Bs[nb][ld0]); ldg16(gb1, &Bs[nb][ld1]);
      ga0 += 32; ga1 += 32; gb0 += 32; gb1 += 32;
    }
    bf16x8 af[4], bfr[4];
#pragma unroll
    for (int mt = 0; mt < 4; mt++)
      af[mt] = __builtin_bit_cast(bf16x8, *(const ushortx8*)&As[cur][aoff + mt * 512]);
#pragma unroll
    for (int nt = 0; nt < 4; nt++)
      bfr[nt] = __builtin_bit_cast(bf16x8, *(const ushortx8*)&Bs[cur][boff + nt * 512]);
#pragma unroll
    for (int mt = 0; mt < 4; mt++)
#pragma unroll
      for (int nt = 0; nt < 4; nt++)
        acc[mt][nt] = __builtin_amdgcn_mfma_f32_16x16x32_bf16(af[mt], bfr[nt], acc[mt][nt], 0, 0, 0);
    __syncthreads();
  }

  int mrem = Nexp - m0;
#pragma unroll
  for (int mt = 0; mt < 4; mt++) {
    int rbase = wm * 64 + mt * 16 + quad * 4;
#pragma unroll
    for (int nt = 0; nt < 4; nt++) {
      int col = wn * 64 + nt * 16 + l15;
      float bb = b1[e * FFN + n0 + col];
#pragma unroll
      for (int r = 0; r < 4; r++) {
        int rr = rbase + r;
        if (rr < mrem) {
          float v = acc[mt][nt][r] + bb;
          v = 0.5f * v * (1.0f + erff(v * 0.70710678118654752f));  // exact gelu
          hbuf[(size_t)(gbase + rr) * FFN + n0 + col] = f2bf(v);
        }
      }
    }
  }
}

// ---------------- GEMM2: Out += (H W2^T [+ b2]) * gate, split-K=4 ----------------
__global__ __launch_bounds__(256, 4) void gemm2_kernel(
    const unsigned short* __restrict__ hbuf, const unsigned short* __restrict__ w2b,
    const float* __restrict__ b2, const int* __restrict__ counts,
    const int* __restrict__ offsets, const int* __restrict__ perm,
    const float* __restrict__ wgtg, float* __restrict__ out) {
  int e = blockIdx.z & 7, kz = blockIdx.z >> 3;
  int Nexp = counts[e];
  int m0 = blockIdx.y * 128;
  if (m0 >= Nexp) return;
  int n0 = blockIdx.x * 128;
  int k0 = kz * (FFN / 4);
  int gbase = offsets[e] + m0;

  __shared__ unsigned short As[2][128 * 32];
  __shared__ unsigned short Bs[2][128 * 32];

  int tid = threadIdx.x, lane = tid & 63, w = tid >> 6;
  int rl = lane >> 2, kbp = lane & 3;
  int rA0 = w * 32 + rl, rA1 = rA0 + 16;
  int s0 = (rA0 + (rA0 >> 2)) & 3, s1 = (rA1 + (rA1 >> 2)) & 3;
  const unsigned short* w2e = w2b + (size_t)e * (HID * FFN);
  const unsigned short* ga0 = hbuf + (size_t)(gbase + rA0) * FFN + k0 + (kbp ^ s0) * 8;
  const unsigned short* ga1 = hbuf + (size_t)(gbase + rA1) * FFN + k0 + (kbp ^ s1) * 8;
  const unsigned short* gb0 = w2e + (size_t)(n0 + rA0) * FFN + k0 + (kbp ^ s0) * 8;
  const unsigned short* gb1 = w2e + (size_t)(n0 + rA1) * FFN + k0 + (kbp ^ s1) * 8;
  const int ld0 = (w * 32) * 32, ld1 = (w * 32 + 16) * 32;

  int wm = w & 1, wn = w >> 1, quad = lane >> 4, l15 = lane & 15;
  int sl = (l15 + (l15 >> 2)) & 3;
  const int aoff = (wm * 64 + l15) * 32 + (quad ^ sl) * 8;
  const int boff = (wn * 64 + l15) * 32 + (quad ^ sl) * 8;
  f32x4 acc[4][4] = {};

  ldg16(ga0, &As[0][ld0]); ldg16(ga1, &As[0][ld1]);
  ldg16(gb0, &Bs[0][ld0]); ldg16(gb1, &Bs[0][ld1]);
  ga0 += 32; ga1 += 32; gb0 += 32; gb1 += 32;
  __syncthreads();

  const int NK = (FFN / 4) / 32;  // 32
  for (int kk = 0; kk < NK; kk++) {
    int cur = kk & 1;
    if (kk + 1 < NK) {
      int nb = cur ^ 1;
      ldg16(ga0, &As[nb][ld0]); ldg16(ga1, &As[nb][ld1]);
      ldg16(gb0, &Bs[nb][ld0]); ldg16(gb1, &Bs[nb][ld1]);
      ga0 += 32; ga1 += 32; gb0 += 32; gb1 += 32;
    }
    bf16x8 af[4], bfr[4];
#pragma unroll
    for (int mt = 0; mt < 4; mt++)
      af[mt] = __builtin_bit_cast(bf16x8, *(const ushortx8*)&As[cur][aoff + mt * 512]);
#pragma unroll
    for (int nt = 0; nt < 4; nt++)
      bfr[nt] = __builtin_bit_cast(bf16x8, *(const ushortx8*)&Bs[cur][boff + nt * 512]);
#pragma unroll
    for (int mt = 0; mt < 4; mt++)
#pragma unroll
      for (int nt = 0; nt < 4; nt++)
        acc[mt][nt] = __builtin_amdgcn_mfma_f32_16x16x32_bf16(af[mt], bfr[nt], acc[mt][nt], 0, 0, 0);
    __syncthreads();
  }

  int mrem = Nexp - m0;
#pragma unroll
  for (int mt = 0; mt < 4; mt++) {
    int rbase = wm * 64 + mt * 16 + quad * 4;
    int tk[4]; float gt[4];
#pragma unroll
    for (int r = 0; r < 4; r++) {
      int ri = gbase + rbase + r; if (ri > NT - 1) ri = NT - 1;
      tk[r] = perm[ri]; gt[r] = wgtg[ri];
    }
#pragma unroll
    for (int nt = 0; nt < 4; nt++) {
      int col = wn * 64 + nt * 16 + l15;
      float bb = b2[e * HID + n0 + col];
#pragma unroll
      for (int r = 0; r < 4; r++) {
        int rr = rbase + r;
        if (rr < mrem) {
          float v = acc[mt][nt][r];
          if (kz == 0) v += bb;
          atomicAdd(out + (size_t)tk[r] * HID + n0 + col, v * gt[r]);
        }
      }
    }
  }
}

extern "C" void kernel_launch(void* const* d_in, const int* in_sizes, int n_in,
                              void* d_out, int out_size, void* d_ws, size_t ws_size,
                              hipStream_t stream) {
  const float* x  = (const float*)d_in[0];
  const float* rw = (const float*)d_in[1];
  const float* w1 = (const float*)d_in[2];
  const float* b1 = (const float*)d_in[3];
  const float* w2 = (const float*)d_in[4];
  const float* b2 = (const float*)d_in[5];
  float* out = (float*)d_out;

  char* ws = (char*)d_ws;
  int*   counts   = (int*)(ws + 0);
  int*   cursor   = (int*)(ws + 32);
  float* prob_sum = (float*)(ws + 64);
  int*   offsets  = (int*)(ws + 96);
  int*   perm     = (int*)(ws + 256);
  float* wgt      = (float*)(ws + 16640);
  int*   eidx     = (int*)(ws + 33024);
  float* wgtg     = (float*)(ws + 49408);
  unsigned short* xg   = (unsigned short*)(ws + 65792);
  unsigned short* w1b  = (unsigned short*)(ws + 8716544);
  unsigned short* hbuf = (unsigned short*)(ws + 75825408);
  unsigned short* w2b  = (unsigned short*)(ws + 110428416);

  (void)hipMemsetAsync(d_ws, 0, 128, stream);
  (void)hipMemsetAsync(d_out, 0, (size_t)(NT * HID + 1) * sizeof(float), stream);
  wcvt_kernel<<<32768, 256, 0, stream>>>(w1, w2, w1b, w2b);
  router_kernel<<<NT / 4, 256, 0, stream>>>(x, rw, counts, prob_sum, eidx, wgt);
  scan_aux_kernel<<<1, 64, 0, stream>>>(counts, prob_sum, offsets, out + (size_t)NT * HID);
  bucketize_kernel<<<NT / 256, 256, 0, stream>>>(eidx, offsets, cursor, perm);
  xgather_kernel<<<NT, 256, 0, stream>>>(x, perm, wgt, xg, wgtg);
  gemm1_kernel<<<dim3(FFN / 128, NT / 128, NE), 256, 0, stream>>>(xg, w1b, b1, counts, offsets, hbuf);
  gemm2_kernel<<<dim3(HID / 128, NT / 128, NE * 4), 256, 0, stream>>>(hbuf, w2b, b2, counts, offsets, perm, wgtg, out);
}